// Round 5
// baseline (211.591 us; speedup 1.0000x reference)
//
#include <hip/hip_runtime.h>
#include <hip/hip_bf16.h>
#include <cstdint>
#include <cstddef>

typedef _Float16 half8 __attribute__((ext_vector_type(8)));
typedef _Float16 half4 __attribute__((ext_vector_type(4)));
typedef _Float16 half2v __attribute__((ext_vector_type(2)));
typedef float floatx4 __attribute__((ext_vector_type(4)));

#define LOG2E 1.4426950408889634f
#define QSCALE (0.125f * LOG2E)

// async global->LDS, 16B per lane. LDS dest is wave-uniform base (HW adds lane*16).
__device__ __forceinline__ void async_load16(const void* g, void* l) {
  void* gnc = const_cast<void*>(g);
  __builtin_amdgcn_global_load_lds(
      (__attribute__((address_space(1))) void*)(gnc),
      (__attribute__((address_space(3))) void*)(l), 16, 0, 0);
}

// packed f32x2 -> f16x2 (RTZ), bitcast to our half2v
__device__ __forceinline__ half2v cvt_pk_f16(float a, float b) {
  return __builtin_bit_cast(half2v, __builtin_amdgcn_cvt_pkrtz(a, b));
}

// ---------------- fused fp32 -> fp16 cast of x, qkv_w, out_w ----------------
__global__ __launch_bounds__(256) void cvt_all(const float* __restrict__ x,
                                               const float* __restrict__ w1,
                                               const float* __restrict__ w2,
                                               _Float16* __restrict__ xh,
                                               _Float16* __restrict__ w1h,
                                               _Float16* __restrict__ w2h) {
  int i = blockIdx.x * 256 + threadIdx.x;
  const float* src;
  _Float16* dst;
  int off;
  if (i < 1048576) {
    src = x; dst = xh; off = i;
  } else if (i < 1048576 + 786432) {
    src = w1; dst = w1h; off = i - 1048576;
  } else {
    src = w2; dst = w2h; off = i - 1835008;
  }
  float4 v = reinterpret_cast<const float4*>(src)[off];
  half4 h = {(_Float16)v.x, (_Float16)v.y, (_Float16)v.z, (_Float16)v.w};
  reinterpret_cast<half4*>(dst)[off] = h;
}

// ---------------- QKV GEMM: C = X(4096x1024) @ W^T + b, scatter to Q(scaled)/K/V ----------------
// tile 128x128, BK=64, 4 waves (2x2), double-buffered LDS, 1 barrier/iter.
__global__ __launch_bounds__(256) void qkv_gemm(const _Float16* __restrict__ X,
                                                const _Float16* __restrict__ W,
                                                const float* __restrict__ bias,
                                                _Float16* __restrict__ Q,
                                                _Float16* __restrict__ K,
                                                _Float16* __restrict__ V) {
  __shared__ _Float16 As[2][128 * 64];
  __shared__ _Float16 Bs[2][128 * 64];
  const int tid = threadIdx.x;
  const int lane = tid & 63, wid = tid >> 6;
  const int lr = lane & 15, lg = lane >> 4;
  const int bm = blockIdx.x, bn = blockIdx.y;
  const int wm = wid >> 1, wn = wid & 1;
  floatx4 acc[4][4] = {};

  auto stage = [&](int kt, int bsel) {
    const int k0 = kt * 64;
#pragma unroll
    for (int it = 0; it < 4; ++it) {
      int c = it * 256 + (wid << 6) + lane;
      int r = c >> 3, slot = c & 7;
      int cc = slot ^ (r & 7);
      async_load16(X + (size_t)(bm * 128 + r) * 1024 + k0 + cc * 8,
                   &As[bsel][(it * 256 + (wid << 6)) * 8]);
      async_load16(W + (size_t)(bn * 128 + r) * 1024 + k0 + cc * 8,
                   &Bs[bsel][(it * 256 + (wid << 6)) * 8]);
    }
  };

  stage(0, 0);
  __syncthreads();

  for (int kt = 0; kt < 16; ++kt) {
    const int cur = kt & 1;
    if (kt < 15) stage(kt + 1, cur ^ 1);
#pragma unroll
    for (int kf = 0; kf < 2; ++kf) {
      half8 a[4], b[4];
#pragma unroll
      for (int mi = 0; mi < 4; ++mi) {
        int row = wm * 64 + mi * 16 + lr;
        int slot = (kf * 4 + lg) ^ (row & 7);
        a[mi] = *(const half8*)&As[cur][row * 64 + slot * 8];
      }
#pragma unroll
      for (int nj = 0; nj < 4; ++nj) {
        int row = wn * 64 + nj * 16 + lr;
        int slot = (kf * 4 + lg) ^ (row & 7);
        b[nj] = *(const half8*)&Bs[cur][row * 64 + slot * 8];
      }
#pragma unroll
      for (int mi = 0; mi < 4; ++mi)
#pragma unroll
        for (int nj = 0; nj < 4; ++nj)
          acc[mi][nj] = __builtin_amdgcn_mfma_f32_16x16x32_f16(a[mi], b[nj], acc[mi][nj], 0, 0, 0);
    }
    if (kt < 15) __syncthreads();
  }

  // epilogue: j -> (h, q/k/v, d); Q pre-scaled by QSCALE
#pragma unroll
  for (int nj = 0; nj < 4; ++nj) {
    int j = bn * 128 + wn * 64 + nj * 16 + lr;
    float bj = bias[j];
    int h = j / 192, rr = j % 192;
    int typ = rr >> 6, d = rr & 63;
    float scl = (typ == 0) ? QSCALE : 1.0f;
    _Float16* dst = (typ == 0) ? Q : (typ == 1) ? K : V;
#pragma unroll
    for (int mi = 0; mi < 4; ++mi) {
#pragma unroll
      for (int r = 0; r < 4; ++r) {
        int i = bm * 128 + wm * 64 + mi * 16 + lg * 4 + r;
        int b_ = i >> 11, s = i & 2047;
        float v = (acc[mi][nj][r] + bj) * scl;
        dst[(size_t)((b_ * 16 + h) * 2048 + s) * 64 + d] = (_Float16)v;
      }
    }
  }
}

// ---------------- V [bh][2048][64] -> Vp [bh][64][2048], key-permuted per 128-block ----------------
// Vp[d][blk*128 + c'] = V[blk*128 + pi(c')][d], pi(c') = (c'&7)*16 + (c'>>3)
__global__ __launch_bounds__(256) void transpose_v(const _Float16* __restrict__ V,
                                                   _Float16* __restrict__ Vp) {
  __shared__ _Float16 tile[128 * 72];  // [s][d], pad 72 to break bank cycles
  const int t = threadIdx.x;
  const int s0 = blockIdx.x * 128;
  const int bh = blockIdx.y;
  const _Float16* src = V + (size_t)bh * 131072;
#pragma unroll
  for (int it = 0; it < 4; ++it) {
    int c = it * 256 + t;
    int rs = c >> 3, ch = c & 7;
    half8 v = *(const half8*)(src + (size_t)(s0 + rs) * 64 + ch * 8);
    *(half8*)&tile[rs * 72 + ch * 8] = v;
  }
  __syncthreads();
  _Float16* dst = Vp + (size_t)bh * 131072;
  const int rd = t >> 2, q4 = t & 3;  // rd: d-row, q4: quarter of the 128 c'
#pragma unroll
  for (int qq = 0; qq < 4; ++qq) {
    half8 v;
#pragma unroll
    for (int e = 0; e < 8; ++e) {
      int u = e * 16 + q4 * 4 + qq;  // = pi(c'), c' = q4*32 + qq*8 + e
      v[e] = tile[u * 72 + rd];
    }
    *(half8*)(dst + (size_t)rd * 2048 + s0 + q4 * 32 + qq * 8) = v;
  }
}

// ---------------- flash attention with ALiBi ----------------
// grid (32 qtiles, 32 bh), 4 waves x 16 q-rows, KVBLK=128, dh=64.
// 2-stage double-buffered K/V, separate permuted P, 1 barrier/tile.
__global__ __launch_bounds__(256) void attn(const _Float16* __restrict__ Q,
                                            const _Float16* __restrict__ K,
                                            const _Float16* __restrict__ Vp,
                                            _Float16* __restrict__ O) {
  __shared__ _Float16 lds[40960];  // K dbuf 2x8192, V dbuf 2x8192, P 4x(16x128)
  const int tid = threadIdx.x, lane = tid & 63, wid = tid >> 6;
  const int lr = lane & 15, lg = lane >> 4;
  const int qt = blockIdx.x, bh = blockIdx.y;
  const int h = bh & 15, b = bh >> 4;
  const int q0 = qt * 64 + wid * 16;
  const float slopeL2 = exp2f(-(float)h) * LOG2E;  // m^h * log2(e)
  const _Float16* Qg = Q + (size_t)bh * 131072;
  const _Float16* Kg = K + (size_t)bh * 131072;
  const _Float16* Vg = Vp + (size_t)bh * 131072;

  half8 qa[2];  // Q pre-scaled by QSCALE in qkv_gemm
#pragma unroll
  for (int kf = 0; kf < 2; ++kf)
    qa[kf] = *(const half8*)(Qg + (size_t)(q0 + lr) * 64 + kf * 32 + lg * 8);

  float lsum[4] = {0.f, 0.f, 0.f, 0.f};
  floatx4 o[4] = {};
  _Float16* Pw = &lds[32768 + wid * 2048];

  auto stage = [&](int kt, int bsel) {
    const int kv0 = kt * 128;
#pragma unroll
    for (int it = 0; it < 4; ++it) {
      int c = it * 256 + (wid << 6) + lane;
      int rk = c >> 3, sk = c & 7, ck = sk ^ (rk & 7);
      async_load16(Kg + (size_t)(kv0 + rk) * 64 + ck * 8,
                   &lds[bsel * 8192 + (it * 256 + (wid << 6)) * 8]);
      int rv = c >> 4, sv = c & 15, cv = sv ^ (rv & 15);
      async_load16(Vg + (size_t)rv * 2048 + kv0 + cv * 8,
                   &lds[16384 + bsel * 8192 + (it * 256 + (wid << 6)) * 8]);
    }
  };

  stage(0, 0);
  __syncthreads();

  for (int kt = 0; kt < 16; ++kt) {
    const int cur = kt & 1;
    const int kv0 = kt * 128;
    if (kt < 15) stage(kt + 1, cur ^ 1);
    const _Float16* Kb = &lds[cur * 8192];
    const _Float16* Vb = &lds[16384 + cur * 8192];

    // QK^T : scores[16 rows][128 keys] per wave (already x QSCALE)
    floatx4 sc[8];
#pragma unroll
    for (int nj = 0; nj < 8; ++nj) sc[nj] = floatx4{0.f, 0.f, 0.f, 0.f};
#pragma unroll
    for (int nj = 0; nj < 8; ++nj) {
      int row = nj * 16 + lr;
#pragma unroll
      for (int kf = 0; kf < 2; ++kf) {
        int slot = (kf * 4 + lg) ^ (row & 7);
        half8 kb = *(const half8*)&Kb[row * 64 + slot * 8];
        sc[nj] = __builtin_amdgcn_mfma_f32_16x16x32_f16(qa[kf], kb, sc[nj], 0, 0, 0);
      }
    }

    // softmax: p = exp2(sc - dist*slopeL2); pack 8/row -> one b128 store
    const int ibase = q0 + lg * 4 - lr - kv0;
#pragma unroll
    for (int r = 0; r < 4; ++r) {
      const int prow = lg * 4 + r;
      float fj = (float)(ibase + r);
      float p[8];
#pragma unroll
      for (int nj = 0; nj < 8; ++nj) {
        float t = fmaf(fabsf(fj), -slopeL2, sc[nj][r]);
        p[nj] = __builtin_amdgcn_exp2f(t);
        lsum[r] += p[nj];
        fj -= 16.0f;
      }
      union { half8 h8; half2v h2[4]; } u;
#pragma unroll
      for (int c2 = 0; c2 < 4; ++c2)
        u.h2[c2] = cvt_pk_f16(p[2 * c2], p[2 * c2 + 1]);
      *(half8*)&Pw[prow * 128 + (lr ^ prow) * 8] = u.h8;
    }

    // PV : O[16][64] += P[16][128] @ V[128][64] (both in permuted key order)
#pragma unroll
    for (int kf2 = 0; kf2 < 4; ++kf2) {
      int slotp = (kf2 * 4 + lg) ^ lr;
      half8 pa = *(const half8*)&Pw[lr * 128 + slotp * 8];
#pragma unroll
      for (int nd = 0; nd < 4; ++nd) {
        int vrow = nd * 16 + lr;
        int slotv = (kf2 * 4 + lg) ^ (vrow & 15);
        half8 vb = *(const half8*)&Vb[vrow * 128 + slotv * 8];
        o[nd] = __builtin_amdgcn_mfma_f32_16x16x32_f16(pa, vb, o[nd], 0, 0, 0);
      }
    }
    if (kt < 15) __syncthreads();
  }

  // deferred l reduction over the 16 lr-lanes, then epilogue
#pragma unroll
  for (int r = 0; r < 4; ++r) {
#pragma unroll
    for (int x = 1; x < 16; x <<= 1) lsum[r] += __shfl_xor(lsum[r], x, 64);
  }
#pragma unroll
  for (int r = 0; r < 4; ++r) {
    float inv = 1.0f / lsum[r];
    int s = q0 + lg * 4 + r;
#pragma unroll
    for (int nd = 0; nd < 4; ++nd) {
      int d = nd * 16 + lr;
      O[((size_t)(b * 2048 + s)) * 1024 + h * 64 + d] = (_Float16)(o[nd][r] * inv);
    }
  }
}

// ---------------- out GEMM: out = O(4096x1024) @ Wout^T + b (fp32 out) ----------------
__global__ __launch_bounds__(256) void out_gemm(const _Float16* __restrict__ A_,
                                                const _Float16* __restrict__ W,
                                                const float* __restrict__ bias,
                                                float* __restrict__ out) {
  __shared__ _Float16 As[2][128 * 64];
  __shared__ _Float16 Bs[2][128 * 64];
  const int tid = threadIdx.x;
  const int lane = tid & 63, wid = tid >> 6;
  const int lr = lane & 15, lg = lane >> 4;
  const int bm = blockIdx.x, bn = blockIdx.y;
  const int wm = wid >> 1, wn = wid & 1;
  floatx4 acc[4][4] = {};

  auto stage = [&](int kt, int bsel) {
    const int k0 = kt * 64;
#pragma unroll
    for (int it = 0; it < 4; ++it) {
      int c = it * 256 + (wid << 6) + lane;
      int r = c >> 3, slot = c & 7;
      int cc = slot ^ (r & 7);
      async_load16(A_ + (size_t)(bm * 128 + r) * 1024 + k0 + cc * 8,
                   &As[bsel][(it * 256 + (wid << 6)) * 8]);
      async_load16(W + (size_t)(bn * 128 + r) * 1024 + k0 + cc * 8,
                   &Bs[bsel][(it * 256 + (wid << 6)) * 8]);
    }
  };

  stage(0, 0);
  __syncthreads();

  for (int kt = 0; kt < 16; ++kt) {
    const int cur = kt & 1;
    if (kt < 15) stage(kt + 1, cur ^ 1);
#pragma unroll
    for (int kf = 0; kf < 2; ++kf) {
      half8 a[4], b[4];
#pragma unroll
      for (int mi = 0; mi < 4; ++mi) {
        int row = wm * 64 + mi * 16 + lr;
        int slot = (kf * 4 + lg) ^ (row & 7);
        a[mi] = *(const half8*)&As[cur][row * 64 + slot * 8];
      }
#pragma unroll
      for (int nj = 0; nj < 4; ++nj) {
        int row = wn * 64 + nj * 16 + lr;
        int slot = (kf * 4 + lg) ^ (row & 7);
        b[nj] = *(const half8*)&Bs[cur][row * 64 + slot * 8];
      }
#pragma unroll
      for (int mi = 0; mi < 4; ++mi)
#pragma unroll
        for (int nj = 0; nj < 4; ++nj)
          acc[mi][nj] = __builtin_amdgcn_mfma_f32_16x16x32_f16(a[mi], b[nj], acc[mi][nj], 0, 0, 0);
    }
    if (kt < 15) __syncthreads();
  }

#pragma unroll
  for (int nj = 0; nj < 4; ++nj) {
    int j = bn * 128 + wn * 64 + nj * 16 + lr;
    float bj = bias[j];
#pragma unroll
    for (int mi = 0; mi < 4; ++mi) {
#pragma unroll
      for (int r = 0; r < 4; ++r) {
        int i = bm * 128 + wm * 64 + mi * 16 + lg * 4 + r;
        out[(size_t)i * 1024 + j] = acc[mi][nj][r] + bj;
      }
    }
  }
}

extern "C" void kernel_launch(void* const* d_in, const int* in_sizes, int n_in,
                              void* d_out, int out_size, void* d_ws, size_t ws_size,
                              hipStream_t stream) {
  const float* x = (const float*)d_in[0];
  const float* qkv_w = (const float*)d_in[1];
  const float* qkv_b = (const float*)d_in[2];
  const float* out_w = (const float*)d_in[3];
  const float* out_b = (const float*)d_in[4];
  float* out = (float*)d_out;
  char* ws = (char*)d_ws;

  _Float16* xh = (_Float16*)(ws + 0);          // 8 MB
  _Float16* wqh = (_Float16*)(ws + 8388608);   // 6 MB
  _Float16* woh = (_Float16*)(ws + 14680064);  // 2 MB
  _Float16* Qh = (_Float16*)(ws + 16777216);   // 8 MB
  _Float16* Kh = (_Float16*)(ws + 25165824);   // 8 MB
  _Float16* Vh = (_Float16*)(ws + 33554432);   // 8 MB
  _Float16* Vph = (_Float16*)(ws + 41943040);  // 8 MB
  _Float16* Oh = (_Float16*)(ws + 50331648);   // 8 MB  (total 56 MB)

  cvt_all<<<8192, 256, 0, stream>>>(x, qkv_w, out_w, xh, wqh, woh);
  qkv_gemm<<<dim3(32, 24), 256, 0, stream>>>(xh, wqh, qkv_b, Qh, Kh, Vh);
  transpose_v<<<dim3(16, 32), 256, 0, stream>>>(Vh, Vph);
  attn<<<dim3(32, 32), 256, 0, stream>>>(Qh, Kh, Vph, Oh);
  out_gemm<<<dim3(32, 8), 256, 0, stream>>>(Oh, woh, out_b, out);
}

// Round 6
// 198.249 us; speedup vs baseline: 1.0673x; 1.0673x over previous
//
#include <hip/hip_runtime.h>
#include <hip/hip_bf16.h>
#include <cstdint>
#include <cstddef>

typedef _Float16 half8 __attribute__((ext_vector_type(8)));
typedef _Float16 half4 __attribute__((ext_vector_type(4)));
typedef _Float16 half2v __attribute__((ext_vector_type(2)));
typedef float floatx4 __attribute__((ext_vector_type(4)));

#define LOG2E 1.4426950408889634f
#define QSCALE (0.125f * LOG2E)

// async global->LDS, 16B per lane. LDS dest is wave-uniform base (HW adds lane*16).
__device__ __forceinline__ void async_load16(const void* g, void* l) {
  void* gnc = const_cast<void*>(g);
  __builtin_amdgcn_global_load_lds(
      (__attribute__((address_space(1))) void*)(gnc),
      (__attribute__((address_space(3))) void*)(l), 16, 0, 0);
}

// packed f32x2 -> f16x2 (RTZ), bitcast to our half2v
__device__ __forceinline__ half2v cvt_pk_f16(float a, float b) {
  return __builtin_bit_cast(half2v, __builtin_amdgcn_cvt_pkrtz(a, b));
}

// ---------------- fused fp32 -> fp16 cast of x, qkv_w, out_w ----------------
__global__ __launch_bounds__(256) void cvt_all(const float* __restrict__ x,
                                               const float* __restrict__ w1,
                                               const float* __restrict__ w2,
                                               _Float16* __restrict__ xh,
                                               _Float16* __restrict__ w1h,
                                               _Float16* __restrict__ w2h) {
  int i = blockIdx.x * 256 + threadIdx.x;
  const float* src;
  _Float16* dst;
  int off;
  if (i < 1048576) {
    src = x; dst = xh; off = i;
  } else if (i < 1048576 + 786432) {
    src = w1; dst = w1h; off = i - 1048576;
  } else {
    src = w2; dst = w2h; off = i - 1835008;
  }
  float4 v = reinterpret_cast<const float4*>(src)[off];
  half4 h = {(_Float16)v.x, (_Float16)v.y, (_Float16)v.z, (_Float16)v.w};
  reinterpret_cast<half4*>(dst)[off] = h;
}

// ---------------- QKV GEMM: C = X(4096x1024) @ W^T + b, scatter to Q(scaled)/K/V ----------------
// tile 128x128, BK=32, 4 waves (2x2), single buffer, 2 barriers/iter (m97 structure).
__global__ __launch_bounds__(256) void qkv_gemm(const _Float16* __restrict__ X,
                                                const _Float16* __restrict__ W,
                                                const float* __restrict__ bias,
                                                _Float16* __restrict__ Q,
                                                _Float16* __restrict__ K,
                                                _Float16* __restrict__ V) {
  __shared__ _Float16 As[128 * 32];
  __shared__ _Float16 Bs[128 * 32];
  const int tid = threadIdx.x;
  const int lane = tid & 63, wid = tid >> 6;
  const int lr = lane & 15, lg = lane >> 4;
  const int bm = blockIdx.x, bn = blockIdx.y;
  const int wm = wid >> 1, wn = wid & 1;
  floatx4 acc[4][4] = {};

  for (int kt = 0; kt < 32; ++kt) {
    const int k0 = kt * 32;
    __syncthreads();
#pragma unroll
    for (int it = 0; it < 2; ++it) {
      int c = it * 256 + (wid << 6) + lane;
      int r = c >> 2, slot = c & 3;
      int cc = slot ^ ((r >> 1) & 3);
      async_load16(X + (size_t)(bm * 128 + r) * 1024 + k0 + cc * 8,
                   &As[(it * 256 + (wid << 6)) * 8]);
      async_load16(W + (size_t)(bn * 128 + r) * 1024 + k0 + cc * 8,
                   &Bs[(it * 256 + (wid << 6)) * 8]);
    }
    __syncthreads();
    half8 a[4], b[4];
#pragma unroll
    for (int mi = 0; mi < 4; ++mi) {
      int row = wm * 64 + mi * 16 + lr;
      int slot = lg ^ ((row >> 1) & 3);
      a[mi] = *(const half8*)&As[row * 32 + slot * 8];
    }
#pragma unroll
    for (int nj = 0; nj < 4; ++nj) {
      int row = wn * 64 + nj * 16 + lr;
      int slot = lg ^ ((row >> 1) & 3);
      b[nj] = *(const half8*)&Bs[row * 32 + slot * 8];
    }
#pragma unroll
    for (int mi = 0; mi < 4; ++mi)
#pragma unroll
      for (int nj = 0; nj < 4; ++nj)
        acc[mi][nj] = __builtin_amdgcn_mfma_f32_16x16x32_f16(a[mi], b[nj], acc[mi][nj], 0, 0, 0);
  }

  // epilogue: j -> (h, q/k/v, d); Q pre-scaled by QSCALE
#pragma unroll
  for (int nj = 0; nj < 4; ++nj) {
    int j = bn * 128 + wn * 64 + nj * 16 + lr;
    float bj = bias[j];
    int h = j / 192, rr = j % 192;
    int typ = rr >> 6, d = rr & 63;
    float scl = (typ == 0) ? QSCALE : 1.0f;
    _Float16* dst = (typ == 0) ? Q : (typ == 1) ? K : V;
#pragma unroll
    for (int mi = 0; mi < 4; ++mi) {
#pragma unroll
      for (int r = 0; r < 4; ++r) {
        int i = bm * 128 + wm * 64 + mi * 16 + lg * 4 + r;
        int b_ = i >> 11, s = i & 2047;
        float v = (acc[mi][nj][r] + bj) * scl;
        dst[(size_t)((b_ * 16 + h) * 2048 + s) * 64 + d] = (_Float16)v;
      }
    }
  }
}

// ---------------- V [bh][2048][64] -> Vp [bh][64][2048], key-permuted per 64-block ----------------
// Vp[d][blk*64 + u] = V[blk*64 + key(u)][d], key(u) = (u&3)*16 + (u>>2)
__global__ __launch_bounds__(256) void transpose_v(const _Float16* __restrict__ V,
                                                   _Float16* __restrict__ Vp) {
  __shared__ _Float16 tile[128 * 72];  // [s][d], pad 72 to break bank cycles
  const int t = threadIdx.x;
  const int s0 = blockIdx.x * 128;
  const int bh = blockIdx.y;
  const _Float16* src = V + (size_t)bh * 131072;
#pragma unroll
  for (int it = 0; it < 4; ++it) {
    int c = it * 256 + t;
    int rs = c >> 3, ch = c & 7;
    half8 v = *(const half8*)(src + (size_t)(s0 + rs) * 64 + ch * 8);
    *(half8*)&tile[rs * 72 + ch * 8] = v;
  }
  __syncthreads();
  _Float16* dst = Vp + (size_t)bh * 131072;
  const int rd = t >> 2, q4 = t & 3;  // rd: d-row, q4: quarter of the 128 positions
#pragma unroll
  for (int qq = 0; qq < 4; ++qq) {
    half8 v;
#pragma unroll
    for (int e = 0; e < 8; ++e) {
      int p = q4 * 32 + qq * 8 + e;
      int blk = p >> 6, u = p & 63;
      int key = (u & 3) * 16 + (u >> 2);
      v[e] = tile[(blk * 64 + key) * 72 + rd];
    }
    *(half8*)(dst + (size_t)rd * 2048 + s0 + q4 * 32 + qq * 8) = v;
  }
}

// ---------------- flash attention with ALiBi ----------------
// grid (32 qtiles, 32 bh), 4 waves x 16 q-rows, KVBLK=64, dh=64.
// 2-stage double-buffered K/V, per-wave permuted P, 1 barrier/tile, 40KB LDS -> 4 blocks/CU.
__global__ __launch_bounds__(256, 4) void attn(const _Float16* __restrict__ Q,
                                               const _Float16* __restrict__ K,
                                               const _Float16* __restrict__ Vp,
                                               _Float16* __restrict__ O) {
  __shared__ _Float16 lds[20480];  // K dbuf 2x4096, V dbuf 2x4096, P 4x1024 = 40KB
  const int tid = threadIdx.x, lane = tid & 63, wid = tid >> 6;
  const int lr = lane & 15, lg = lane >> 4;
  const int qt = blockIdx.x, bh = blockIdx.y;
  const int h = bh & 15, b = bh >> 4;
  const int q0 = qt * 64 + wid * 16;
  const float slopeL2 = exp2f(-(float)h) * LOG2E;  // m^h * log2(e)
  const _Float16* Qg = Q + (size_t)bh * 131072;
  const _Float16* Kg = K + (size_t)bh * 131072;
  const _Float16* Vg = Vp + (size_t)bh * 131072;

  half8 qa[2];  // Q pre-scaled by QSCALE in qkv_gemm
#pragma unroll
  for (int kf = 0; kf < 2; ++kf)
    qa[kf] = *(const half8*)(Qg + (size_t)(q0 + lr) * 64 + kf * 32 + lg * 8);

  float lsum[4] = {0.f, 0.f, 0.f, 0.f};
  floatx4 o[4] = {};
  _Float16* Pw = &lds[16384 + wid * 1024];

  auto stage = [&](int kt, int bsel) {
    const int kv0 = kt * 64;
#pragma unroll
    for (int it = 0; it < 2; ++it) {
      int c = it * 256 + (wid << 6) + lane;
      int rk = c >> 3, sk = c & 7, ck = sk ^ (rk & 7);
      async_load16(Kg + (size_t)(kv0 + rk) * 64 + ck * 8,
                   &lds[bsel * 4096 + (it * 256 + (wid << 6)) * 8]);
      async_load16(Vg + (size_t)rk * 2048 + kv0 + ck * 8,
                   &lds[8192 + bsel * 4096 + (it * 256 + (wid << 6)) * 8]);
    }
  };

  stage(0, 0);
  __syncthreads();

  for (int kt = 0; kt < 32; ++kt) {
    const int cur = kt & 1;
    const int kv0 = kt * 64;
    if (kt < 31) stage(kt + 1, cur ^ 1);
    const _Float16* Kb = &lds[cur * 4096];
    const _Float16* Vb = &lds[8192 + cur * 4096];

    // QK^T : scores[16 rows][64 keys] per wave (already x QSCALE)
    floatx4 sc[4];
#pragma unroll
    for (int nj = 0; nj < 4; ++nj) sc[nj] = floatx4{0.f, 0.f, 0.f, 0.f};
    __builtin_amdgcn_s_setprio(1);
#pragma unroll
    for (int nj = 0; nj < 4; ++nj) {
      int row = nj * 16 + lr;
#pragma unroll
      for (int kf = 0; kf < 2; ++kf) {
        int slot = (kf * 4 + lg) ^ (row & 7);
        half8 kb = *(const half8*)&Kb[row * 64 + slot * 8];
        sc[nj] = __builtin_amdgcn_mfma_f32_16x16x32_f16(qa[kf], kb, sc[nj], 0, 0, 0);
      }
    }
    __builtin_amdgcn_s_setprio(0);

    // softmax: p = exp2(sc - dist*slopeL2); per row pack 4 -> one b64 store
    const int ibase = q0 + lg * 4 - lr - kv0;
#pragma unroll
    for (int r = 0; r < 4; ++r) {
      const int prow = lg * 4 + r;
      float fj = (float)(ibase + r);
      float p[4];
#pragma unroll
      for (int nj = 0; nj < 4; ++nj) {
        float t = fmaf(fabsf(fj), -slopeL2, sc[nj][r]);
        p[nj] = __builtin_amdgcn_exp2f(t);
        fj -= 16.0f;
      }
      lsum[r] += (p[0] + p[1]) + (p[2] + p[3]);
      union { half4 h4; half2v h2[2]; } u;
      u.h2[0] = cvt_pk_f16(p[0], p[1]);
      u.h2[1] = cvt_pk_f16(p[2], p[3]);
      // P[prow][u-pos lr*4+nj] with 8B-granular XOR swizzle (keeps 16B read pairs)
      *(half4*)&Pw[prow * 64 + (lr ^ ((prow & 7) << 1)) * 4] = u.h4;
    }

    // PV : O[16][64] += P[16][64] @ V[64][64] (both in permuted key order)
    __builtin_amdgcn_s_setprio(1);
#pragma unroll
    for (int kf2 = 0; kf2 < 2; ++kf2) {
      int slotp = ((kf2 << 2) + lg) ^ (lr & 7);
      half8 pa = *(const half8*)&Pw[lr * 64 + slotp * 8];
#pragma unroll
      for (int nd = 0; nd < 4; ++nd) {
        int vrow = nd * 16 + lr;
        int slotv = ((kf2 << 2) + lg) ^ (vrow & 7);
        half8 vb = *(const half8*)&Vb[vrow * 64 + slotv * 8];
        o[nd] = __builtin_amdgcn_mfma_f32_16x16x32_f16(pa, vb, o[nd], 0, 0, 0);
      }
    }
    __builtin_amdgcn_s_setprio(0);
    if (kt < 31) __syncthreads();
  }

  // deferred l reduction over the 16 lr-lanes, then epilogue
#pragma unroll
  for (int r = 0; r < 4; ++r) {
#pragma unroll
    for (int x = 1; x < 16; x <<= 1) lsum[r] += __shfl_xor(lsum[r], x, 64);
  }
#pragma unroll
  for (int r = 0; r < 4; ++r) {
    float inv = 1.0f / lsum[r];
    int s = q0 + lg * 4 + r;
#pragma unroll
    for (int nd = 0; nd < 4; ++nd) {
      int d = nd * 16 + lr;
      O[((size_t)(b * 2048 + s)) * 1024 + h * 64 + d] = (_Float16)(o[nd][r] * inv);
    }
  }
}

// ---------------- out GEMM: out = O(4096x1024) @ Wout^T + b (fp32 out) ----------------
// BK=32 single buffer (m97 structure).
__global__ __launch_bounds__(256) void out_gemm(const _Float16* __restrict__ A_,
                                                const _Float16* __restrict__ W,
                                                const float* __restrict__ bias,
                                                float* __restrict__ out) {
  __shared__ _Float16 As[128 * 32];
  __shared__ _Float16 Bs[128 * 32];
  const int tid = threadIdx.x;
  const int lane = tid & 63, wid = tid >> 6;
  const int lr = lane & 15, lg = lane >> 4;
  const int bm = blockIdx.x, bn = blockIdx.y;
  const int wm = wid >> 1, wn = wid & 1;
  floatx4 acc[4][4] = {};

  for (int kt = 0; kt < 32; ++kt) {
    const int k0 = kt * 32;
    __syncthreads();
#pragma unroll
    for (int it = 0; it < 2; ++it) {
      int c = it * 256 + (wid << 6) + lane;
      int r = c >> 2, slot = c & 3;
      int cc = slot ^ ((r >> 1) & 3);
      async_load16(A_ + (size_t)(bm * 128 + r) * 1024 + k0 + cc * 8,
                   &As[(it * 256 + (wid << 6)) * 8]);
      async_load16(W + (size_t)(bn * 128 + r) * 1024 + k0 + cc * 8,
                   &Bs[(it * 256 + (wid << 6)) * 8]);
    }
    __syncthreads();
    half8 a[4], b[4];
#pragma unroll
    for (int mi = 0; mi < 4; ++mi) {
      int row = wm * 64 + mi * 16 + lr;
      int slot = lg ^ ((row >> 1) & 3);
      a[mi] = *(const half8*)&As[row * 32 + slot * 8];
    }
#pragma unroll
    for (int nj = 0; nj < 4; ++nj) {
      int row = wn * 64 + nj * 16 + lr;
      int slot = lg ^ ((row >> 1) & 3);
      b[nj] = *(const half8*)&Bs[row * 32 + slot * 8];
    }
#pragma unroll
    for (int mi = 0; mi < 4; ++mi)
#pragma unroll
      for (int nj = 0; nj < 4; ++nj)
        acc[mi][nj] = __builtin_amdgcn_mfma_f32_16x16x32_f16(a[mi], b[nj], acc[mi][nj], 0, 0, 0);
  }

#pragma unroll
  for (int nj = 0; nj < 4; ++nj) {
    int j = bn * 128 + wn * 64 + nj * 16 + lr;
    float bj = bias[j];
#pragma unroll
    for (int mi = 0; mi < 4; ++mi) {
#pragma unroll
      for (int r = 0; r < 4; ++r) {
        int i = bm * 128 + wm * 64 + mi * 16 + lg * 4 + r;
        out[(size_t)i * 1024 + j] = acc[mi][nj][r] + bj;
      }
    }
  }
}

extern "C" void kernel_launch(void* const* d_in, const int* in_sizes, int n_in,
                              void* d_out, int out_size, void* d_ws, size_t ws_size,
                              hipStream_t stream) {
  const float* x = (const float*)d_in[0];
  const float* qkv_w = (const float*)d_in[1];
  const float* qkv_b = (const float*)d_in[2];
  const float* out_w = (const float*)d_in[3];
  const float* out_b = (const float*)d_in[4];
  float* out = (float*)d_out;
  char* ws = (char*)d_ws;

  _Float16* xh = (_Float16*)(ws + 0);          // 8 MB
  _Float16* wqh = (_Float16*)(ws + 8388608);   // 6 MB
  _Float16* woh = (_Float16*)(ws + 14680064);  // 2 MB
  _Float16* Qh = (_Float16*)(ws + 16777216);   // 8 MB
  _Float16* Kh = (_Float16*)(ws + 25165824);   // 8 MB
  _Float16* Vh = (_Float16*)(ws + 33554432);   // 8 MB
  _Float16* Vph = (_Float16*)(ws + 41943040);  // 8 MB
  _Float16* Oh = (_Float16*)(ws + 50331648);   // 8 MB  (total 56 MB)

  cvt_all<<<8192, 256, 0, stream>>>(x, qkv_w, out_w, xh, wqh, woh);
  qkv_gemm<<<dim3(32, 24), 256, 0, stream>>>(xh, wqh, qkv_b, Qh, Kh, Vh);
  transpose_v<<<dim3(16, 32), 256, 0, stream>>>(Vh, Vph);
  attn<<<dim3(32, 32), 256, 0, stream>>>(Qh, Kh, Vph, Oh);
  out_gemm<<<dim3(32, 8), 256, 0, stream>>>(Oh, woh, out_b, out);
}